// Round 3
// baseline (499.895 us; speedup 1.0000x reference)
//
#include <hip/hip_runtime.h>
#include <hip/hip_bf16.h>

// Problem constants (from reference)
#define NH   32
#define HD   128
#define NKV  8
#define GQ   4        // NH / NKV
#define BS   16
#define NB   4096
#define MB   128
#define SEQ  32
#define WPG  8        // workgroups per (s,h)
#define UPW  8        // half-wave units per workgroup (256 thr / 32)
#define NSPLIT (WPG*UPW)   // 64 strided splits per (s,h)

__constant__ float SCALE_RSQRT = 0.08838834764831845f; // 1/sqrt(128)

typedef float v2f __attribute__((ext_vector_type(2)));

// RNE round f32 -> bf16 -> f32
__device__ __forceinline__ float bf16r(float x) {
  unsigned u = __float_as_uint(x);
  u = (u + 0x7fffu + ((u >> 16) & 1u)) & 0xffff0000u;
  return __uint_as_float(u);
}

// Dequant 4 cache floats: fp8(e4m3fn, RNE) round, * scale, bf16 RNE round.
__device__ __forceinline__ float4 deq4(float4 x, float sc) {
  int p0 = __builtin_amdgcn_cvt_pk_fp8_f32(x.x, x.y, 0, false);
  int p1 = __builtin_amdgcn_cvt_pk_fp8_f32(x.z, x.w, 0, false);
  v2f a = __builtin_amdgcn_cvt_pk_f32_fp8(p0, false);
  v2f b = __builtin_amdgcn_cvt_pk_f32_fp8(p1, false);
  float4 r;
  r.x = bf16r(a.x * sc);
  r.y = bf16r(a.y * sc);
  r.z = bf16r(b.x * sc);
  r.w = bf16r(b.y * sc);
  return r;
}

// ---------------------------------------------------------------------------
// Split-K flash decode. Unit u (32 lanes) of 64 owns tokens {u, u+64, ...}.
// Steady loop: 2 batches of 4 tokens, 16 loads issued before any use.
// o_part: [SEQ][NKV][WPG][GQ][HD] f32 ; ml_part: [SEQ][NKV][WPG][GQ] float2
// ---------------------------------------------------------------------------
__global__ __launch_bounds__(256, 4)
void attn_split(const float* __restrict__ q,
                const float* __restrict__ knew,
                const float* __restrict__ vnew,
                const float* __restrict__ k_cache,
                const float* __restrict__ v_cache,
                const float* __restrict__ k_scale,
                const float* __restrict__ v_scale,
                const int* __restrict__ block_tables,
                const int* __restrict__ context_lens,
                float* __restrict__ o_part,
                float2* __restrict__ ml_part) {
  const int wg = blockIdx.x;
  const int wgsub = wg % WPG;
  const int h = (wg / WPG) % NKV;
  const int s = wg / (WPG * NKV);
  const int tid = threadIdx.x;
  const int lane = tid & 31;
  const int unit = tid >> 5;            // 0..7 within WG
  const int ug = wgsub * UPW + unit;    // 0..63 global split id
  const int dbase = lane * 4;

  __shared__ int bt[MB];                // this seq's block table
  __shared__ float so[UPW][GQ][HD];     // 16 KB epilogue buffer
  __shared__ float2 sml[UPW][GQ];

  if (tid < MB) bt[tid] = block_tables[s * MB + tid];
  __syncthreads();

  const int ctx = context_lens[s];
  const int last = ctx - 1;             // fresh token position
  const float ks = k_scale[h];
  const float vs = v_scale[h];

  // q fragment, pre-scaled
  float4 qv[GQ];
#pragma unroll
  for (int g = 0; g < GQ; ++g) {
    float4 t = *(const float4*)(q + ((size_t)s * NH + h * GQ + g) * HD + dbase);
    qv[g].x = t.x * SCALE_RSQRT;
    qv[g].y = t.y * SCALE_RSQRT;
    qv[g].z = t.z * SCALE_RSQRT;
    qv[g].w = t.w * SCALE_RSQRT;
  }

  float m[GQ], l[GQ];
  float4 oacc[GQ];
#pragma unroll
  for (int g = 0; g < GQ; ++g) {
    m[g] = -1e30f;
    l[g] = 0.0f;
    oacc[g] = make_float4(0.f, 0.f, 0.f, 0.f);
  }

  const bool owns_last = (ug == (last & (NSPLIT - 1)));

  // ---- fresh token: quantize from knew/vnew (cache slot is stale)
  if (owns_last) {
    float4 kk = *(const float4*)(knew + ((size_t)s * NKV + h) * HD + dbase);
    float4 vt = *(const float4*)(vnew + ((size_t)s * NKV + h) * HD + dbase);
    kk.x /= ks; kk.y /= ks; kk.z /= ks; kk.w /= ks;
    vt.x /= vs; vt.y /= vs; vt.z /= vs; vt.w /= vs;
    kk = deq4(kk, ks);
    vt = deq4(vt, vs);
#pragma unroll
    for (int g = 0; g < GQ; ++g) {
      float d = kk.x * qv[g].x + kk.y * qv[g].y + kk.z * qv[g].z + kk.w * qv[g].w;
      d += __shfl_xor(d, 1);
      d += __shfl_xor(d, 2);
      d += __shfl_xor(d, 4);
      d += __shfl_xor(d, 8);
      d += __shfl_xor(d, 16);
      m[g] = d;
      l[g] = 1.0f;
      oacc[g] = vt;
    }
  }

  // `last` is always the FINAL strided token of its owning unit, so clamping
  // the end excludes exactly it and the steady loop needs no per-token mask.
  const int tend = owns_last ? last : ctx;
  const int n = (tend > ug) ? ((tend - ug + NSPLIT - 1) >> 6) : 0;

  // per-4-token-batch processor (unconditional)
#define PROCESS4(KK, VV)                                                      \
  do {                                                                        \
    float sc_[4][GQ];                                                         \
    _Pragma("unroll") for (int i_ = 0; i_ < 4; ++i_) {                        \
      float4 kd_ = deq4(KK[i_], ks);                                          \
      _Pragma("unroll") for (int g_ = 0; g_ < GQ; ++g_) {                     \
        float d_ = kd_.x * qv[g_].x + kd_.y * qv[g_].y + kd_.z * qv[g_].z +   \
                   kd_.w * qv[g_].w;                                          \
        d_ += __shfl_xor(d_, 1);                                              \
        d_ += __shfl_xor(d_, 2);                                              \
        d_ += __shfl_xor(d_, 4);                                              \
        d_ += __shfl_xor(d_, 8);                                              \
        d_ += __shfl_xor(d_, 16);                                             \
        sc_[i_][g_] = d_;                                                     \
      }                                                                       \
    }                                                                         \
    float4 vd_[4];                                                            \
    _Pragma("unroll") for (int i_ = 0; i_ < 4; ++i_) vd_[i_] = deq4(VV[i_], vs); \
    _Pragma("unroll") for (int g_ = 0; g_ < GQ; ++g_) {                       \
      float tm_ = fmaxf(fmaxf(sc_[0][g_], sc_[1][g_]),                        \
                        fmaxf(sc_[2][g_], sc_[3][g_]));                       \
      float mnew_ = fmaxf(m[g_], tm_);                                        \
      float alpha_ = __expf(m[g_] - mnew_);                                   \
      float p0_ = __expf(sc_[0][g_] - mnew_);                                 \
      float p1_ = __expf(sc_[1][g_] - mnew_);                                 \
      float p2_ = __expf(sc_[2][g_] - mnew_);                                 \
      float p3_ = __expf(sc_[3][g_] - mnew_);                                 \
      l[g_] = l[g_] * alpha_ + (p0_ + p1_ + p2_ + p3_);                       \
      oacc[g_].x = oacc[g_].x * alpha_ + p0_ * vd_[0].x + p1_ * vd_[1].x +    \
                   p2_ * vd_[2].x + p3_ * vd_[3].x;                           \
      oacc[g_].y = oacc[g_].y * alpha_ + p0_ * vd_[0].y + p1_ * vd_[1].y +    \
                   p2_ * vd_[2].y + p3_ * vd_[3].y;                           \
      oacc[g_].z = oacc[g_].z * alpha_ + p0_ * vd_[0].z + p1_ * vd_[1].z +    \
                   p2_ * vd_[2].z + p3_ * vd_[3].z;                           \
      oacc[g_].w = oacc[g_].w * alpha_ + p0_ * vd_[0].w + p1_ * vd_[1].w +    \
                   p2_ * vd_[2].w + p3_ * vd_[3].w;                           \
      m[g_] = mnew_;                                                          \
    }                                                                         \
  } while (0)

  int j = 0;
  // ---- steady loop: 8 tokens (2 batches), 16 loads in flight before use
  for (; j + 8 <= n; j += 8) {
    float4 kA[4], vA[4], kB[4], vB[4];
#pragma unroll
    for (int i = 0; i < 4; ++i) {
      int t = ug + ((j + i) << 6);
      int blk = bt[t >> 4];
      size_t off = (((size_t)blk * BS + (t & (BS - 1))) * NKV + h) * HD + dbase;
      kA[i] = *(const float4*)(k_cache + off);
      vA[i] = *(const float4*)(v_cache + off);
    }
#pragma unroll
    for (int i = 0; i < 4; ++i) {
      int t = ug + ((j + 4 + i) << 6);
      int blk = bt[t >> 4];
      size_t off = (((size_t)blk * BS + (t & (BS - 1))) * NKV + h) * HD + dbase;
      kB[i] = *(const float4*)(k_cache + off);
      vB[i] = *(const float4*)(v_cache + off);
    }
    PROCESS4(kA, vA);
    PROCESS4(kB, vB);
  }

  // ---- tail: one token at a time (≤7 iterations)
  for (; j < n; ++j) {
    int t = ug + (j << 6);
    int blk = bt[t >> 4];
    size_t off = (((size_t)blk * BS + (t & (BS - 1))) * NKV + h) * HD + dbase;
    float4 kk = *(const float4*)(k_cache + off);
    float4 vt = *(const float4*)(v_cache + off);
    float4 kd = deq4(kk, ks);
    float4 vd = deq4(vt, vs);
#pragma unroll
    for (int g = 0; g < GQ; ++g) {
      float d = kd.x * qv[g].x + kd.y * qv[g].y + kd.z * qv[g].z + kd.w * qv[g].w;
      d += __shfl_xor(d, 1);
      d += __shfl_xor(d, 2);
      d += __shfl_xor(d, 4);
      d += __shfl_xor(d, 8);
      d += __shfl_xor(d, 16);
      float mnew = fmaxf(m[g], d);
      float alpha = __expf(m[g] - mnew);
      float p = __expf(d - mnew);
      l[g] = l[g] * alpha + p;
      oacc[g].x = oacc[g].x * alpha + p * vd.x;
      oacc[g].y = oacc[g].y * alpha + p * vd.y;
      oacc[g].z = oacc[g].z * alpha + p * vd.z;
      oacc[g].w = oacc[g].w * alpha + p * vd.w;
      m[g] = mnew;
    }
  }

  // ---- intra-WG combine of the 8 units
#pragma unroll
  for (int g = 0; g < GQ; ++g)
    *(float4*)&so[unit][g][dbase] = oacc[g];
  if (lane == 0) {
#pragma unroll
    for (int g = 0; g < GQ; ++g) sml[unit][g] = make_float2(m[g], l[g]);
  }
  __syncthreads();

  if (tid < 128) {
    int g = tid >> 5;
    int ln = tid & 31;
    float M = -1e30f;
#pragma unroll
    for (int u = 0; u < UPW; ++u) M = fmaxf(M, sml[u][g].x);
    float L = 0.f;
    float4 acc = make_float4(0.f, 0.f, 0.f, 0.f);
#pragma unroll
    for (int u = 0; u < UPW; ++u) {
      float w = __expf(sml[u][g].x - M);
      L += sml[u][g].y * w;
      float4 t = *(const float4*)&so[u][g][ln * 4];
      acc.x += w * t.x;
      acc.y += w * t.y;
      acc.z += w * t.z;
      acc.w += w * t.w;
    }
    size_t ob = ((((size_t)s * NKV + h) * WPG + wgsub) * GQ + g) * HD + ln * 4;
    *(float4*)(o_part + ob) = acc;
    if (ln == 0)
      ml_part[(((size_t)s * NKV + h) * WPG + wgsub) * GQ + g] = make_float2(M, L);
  }
}

// ---------------------------------------------------------------------------
// Combine the WPG workgroup partials per (s,h)
// ---------------------------------------------------------------------------
__global__ void combine_splits(const float* __restrict__ o_part,
                               const float2* __restrict__ ml_part,
                               float* __restrict__ out) {
  int b = blockIdx.x;      // s*NKV + h
  int h = b % NKV;
  int s = b / NKV;
  int d = threadIdx.x;     // 0..127
#pragma unroll
  for (int g = 0; g < GQ; ++g) {
    float2 ml[WPG];
    float M = -1e30f;
#pragma unroll
    for (int i = 0; i < WPG; ++i) {
      ml[i] = ml_part[(((size_t)s * NKV + h) * WPG + i) * GQ + g];
      M = fmaxf(M, ml[i].x);
    }
    float L = 0.f;
    float acc = 0.f;
#pragma unroll
    for (int i = 0; i < WPG; ++i) {
      float w = __expf(ml[i].x - M);
      L += ml[i].y * w;
      acc += w * o_part[((((size_t)s * NKV + h) * WPG + i) * GQ + g) * HD + d];
    }
    out[((size_t)s * NH + h * GQ + g) * HD + d] = acc / L;
  }
}

// ---------------------------------------------------------------------------
extern "C" void kernel_launch(void* const* d_in, const int* in_sizes, int n_in,
                              void* d_out, int out_size, void* d_ws, size_t ws_size,
                              hipStream_t stream) {
  const float* q        = (const float*)d_in[0];
  const float* k        = (const float*)d_in[1];
  const float* v        = (const float*)d_in[2];
  const float* k_cache  = (const float*)d_in[3];
  const float* v_cache  = (const float*)d_in[4];
  const float* k_scale  = (const float*)d_in[5];
  const float* v_scale  = (const float*)d_in[6];
  const int*   btables  = (const int*)d_in[8];
  const int*   ctx_lens = (const int*)d_in[9];
  float*       out      = (float*)d_out;

  float*  o_part  = (float*)d_ws;
  float2* ml_part = (float2*)((char*)d_ws +
                     (size_t)SEQ * NKV * WPG * GQ * HD * sizeof(float));

  attn_split<<<SEQ * NKV * WPG, 256, 0, stream>>>(
      q, k, v, k_cache, v_cache, k_scale, v_scale, btables, ctx_lens,
      o_part, ml_part);

  combine_splits<<<SEQ * NKV, 128, 0, stream>>>(o_part, ml_part, out);
}

// Round 4
// 488.504 us; speedup vs baseline: 1.0233x; 1.0233x over previous
//
#include <hip/hip_runtime.h>
#include <hip/hip_bf16.h>

// Problem constants (from reference)
#define NH   32
#define HD   128
#define NKV  8
#define GQ   4        // NH / NKV
#define BS   16
#define NB   4096
#define MB   128
#define SEQ  32
#define WPG  8        // workgroups per (s,h)
#define UPW  8        // 32-lane units per workgroup (256 thr / 32)
#define NSPLIT (WPG*UPW)   // 64 strided splits per (s,h)
#define TI   2        // tokens per unit per tile
#define NBUF 2        // double buffer

// s_waitcnt simm16 (gfx9): vm[3:0] | exp[6:4] | lgkm[11:8] | vm[5:4]@[15:14]
#define WAIT_VM4 0x0F74   // vmcnt<=4, lgkm/exp untouched
#define WAIT_VM0 0x0F70   // vmcnt<=0

#define AS1 __attribute__((address_space(1)))
#define AS3 __attribute__((address_space(3)))

__constant__ float SCALE_RSQRT = 0.08838834764831845f; // 1/sqrt(128)

typedef float v2f __attribute__((ext_vector_type(2)));

// RNE round f32 -> bf16 -> f32
__device__ __forceinline__ float bf16r(float x) {
  unsigned u = __float_as_uint(x);
  u = (u + 0x7fffu + ((u >> 16) & 1u)) & 0xffff0000u;
  return __uint_as_float(u);
}

// fp8(e4m3fn, RNE) round, * scale, bf16 RNE round (matches reference numerics)
__device__ __forceinline__ float4 deq4(float4 x, float sc) {
  int p0 = __builtin_amdgcn_cvt_pk_fp8_f32(x.x, x.y, 0, false);
  int p1 = __builtin_amdgcn_cvt_pk_fp8_f32(x.z, x.w, 0, false);
  v2f a = __builtin_amdgcn_cvt_pk_f32_fp8(p0, false);
  v2f b = __builtin_amdgcn_cvt_pk_f32_fp8(p1, false);
  float4 r;
  r.x = bf16r(a.x * sc);
  r.y = bf16r(a.y * sc);
  r.z = bf16r(b.x * sc);
  r.w = bf16r(b.y * sc);
  return r;
}

// ---------------------------------------------------------------------------
// Split-K flash decode with async global->LDS double-buffered staging.
// Unit u (32 lanes) of 64 owns tokens {u, u+64, ...}. Staging is wave-local
// (lane L stages the unit it computes), so the main loop has NO barriers;
// tile readiness is a manual s_waitcnt vmcnt(4).
// o_part: [SEQ][NKV][WPG][GQ][HD] f32 ; ml_part: [SEQ][NKV][WPG][GQ] float2
// ---------------------------------------------------------------------------
__global__ __launch_bounds__(256, 4)
void attn_split(const float* __restrict__ q,
                const float* __restrict__ knew,
                const float* __restrict__ vnew,
                const float* __restrict__ k_cache,
                const float* __restrict__ v_cache,
                const float* __restrict__ k_scale,
                const float* __restrict__ v_scale,
                const int* __restrict__ block_tables,
                const int* __restrict__ context_lens,
                float* __restrict__ o_part,
                float2* __restrict__ ml_part) {
  const int wg = blockIdx.x;
  const int wgsub = wg % WPG;
  const int h = (wg / WPG) % NKV;
  const int s = wg / (WPG * NKV);
  const int tid = threadIdx.x;
  const int lane = tid & 31;
  const int unit = tid >> 5;            // 0..7
  const int wave = tid >> 6;            // 0..3
  const int uw = unit & 1;              // unit-in-wave
  const int ug = wgsub * UPW + unit;    // 0..63 global split id
  const int dbase = lane * 4;           // float offset; lane*16B

  __shared__ int bt[MB];
  __shared__ __align__(16) float ldsK[NBUF][4][TI][256]; // 16 KB
  __shared__ __align__(16) float ldsV[NBUF][4][TI][256]; // 16 KB
  __shared__ float2 sml[UPW][GQ];

  if (tid < MB) bt[tid] = block_tables[s * MB + tid];
  __syncthreads();

  const int ctx = context_lens[s];
  const int last = ctx - 1;             // fresh token position
  const float ks = k_scale[h];
  const float vs = v_scale[h];

  // q fragment, pre-scaled
  float4 qv[GQ];
#pragma unroll
  for (int g = 0; g < GQ; ++g) {
    float4 t = *(const float4*)(q + ((size_t)s * NH + h * GQ + g) * HD + dbase);
    qv[g].x = t.x * SCALE_RSQRT;
    qv[g].y = t.y * SCALE_RSQRT;
    qv[g].z = t.z * SCALE_RSQRT;
    qv[g].w = t.w * SCALE_RSQRT;
  }

  float m[GQ], l[GQ];
  float4 oacc[GQ];
#pragma unroll
  for (int g = 0; g < GQ; ++g) {
    m[g] = -1e30f;
    l[g] = 0.0f;
    oacc[g] = make_float4(0.f, 0.f, 0.f, 0.f);
  }

  const bool owns_last = (ug == (last & (NSPLIT - 1)));

  // ---- fresh token: quantize from knew/vnew (cache slot is stale)
  if (owns_last) {
    float4 kk = *(const float4*)(knew + ((size_t)s * NKV + h) * HD + dbase);
    float4 vt = *(const float4*)(vnew + ((size_t)s * NKV + h) * HD + dbase);
    kk.x /= ks; kk.y /= ks; kk.z /= ks; kk.w /= ks;
    vt.x /= vs; vt.y /= vs; vt.z /= vs; vt.w /= vs;
    kk = deq4(kk, ks);
    vt = deq4(vt, vs);
#pragma unroll
    for (int g = 0; g < GQ; ++g) {
      float d = kk.x * qv[g].x + kk.y * qv[g].y + kk.z * qv[g].z + kk.w * qv[g].w;
      d += __shfl_xor(d, 1);
      d += __shfl_xor(d, 2);
      d += __shfl_xor(d, 4);
      d += __shfl_xor(d, 8);
      d += __shfl_xor(d, 16);
      m[g] = d;
      l[g] = 1.0f;
      oacc[g] = vt;
    }
  }

  // `last` is the FINAL strided token of its owning unit, so clamping the end
  // excludes exactly it; no per-token mask beyond t < tend.
  const int tend = owns_last ? last : ctx;
  const int n = (tend > ug) ? ((tend - ug + NSPLIT - 1) >> 6) : 0;
  const int tmax = max(tend - 1, ug);   // safe clamp target for OOB staging

  // wave-uniform tile count (other unit of this wave)
  const int ug_o = ug ^ 1;
  const int tend_o = (ug_o == (last & (NSPLIT - 1))) ? last : ctx;
  const int n_o = (tend_o > ug_o) ? ((tend_o - ug_o + NSPLIT - 1) >> 6) : 0;
  const int nw = max(n, n_o);
  const int ntile = (nw + TI - 1) / TI;

  // stage TI tokens of this lane's unit into buffer B (4 VMEM instrs/wave)
#define STAGE(JB, B)                                                          \
  do {                                                                        \
    _Pragma("unroll") for (int i_ = 0; i_ < TI; ++i_) {                       \
      int t_ = ug + ((JB) + i_) * NSPLIT;                                     \
      t_ = min(t_, tmax);                                                     \
      int blk_ = bt[t_ >> 4];                                                 \
      size_t off_ = (((size_t)blk_ * BS + (t_ & (BS - 1))) * NKV + h) * HD +  \
                    dbase;                                                    \
      __builtin_amdgcn_global_load_lds(                                       \
          (const AS1 void*)(k_cache + off_),                                  \
          (AS3 void*)&ldsK[B][wave][i_][0], 16, 0, 0);                        \
      __builtin_amdgcn_global_load_lds(                                       \
          (const AS1 void*)(v_cache + off_),                                  \
          (AS3 void*)&ldsV[B][wave][i_][0], 16, 0, 0);                        \
    }                                                                         \
  } while (0)

  if (ntile > 0) STAGE(0, 0);

  for (int j = 0, b = 0; j < ntile; ++j, b ^= 1) {
    if (j + 1 < ntile) {
      STAGE((j + 1) * TI, b ^ 1);
      __builtin_amdgcn_s_waitcnt(WAIT_VM4);  // tile j's 4 DMAs drained
    } else {
      __builtin_amdgcn_s_waitcnt(WAIT_VM0);
    }

    // ---- consume tile j from buffer b
    float sc_[TI][GQ];
    float4 vd_[TI];
#pragma unroll
    for (int i = 0; i < TI; ++i) {
      float4 kk = *(const float4*)&ldsK[b][wave][i][uw * 128 + dbase];
      float4 vv = *(const float4*)&ldsV[b][wave][i][uw * 128 + dbase];
      float4 kd = deq4(kk, ks);
      vd_[i] = deq4(vv, vs);
      int t = ug + (j * TI + i) * NSPLIT;
      bool valid = (t < tend);
#pragma unroll
      for (int g = 0; g < GQ; ++g) {
        float d = kd.x * qv[g].x + kd.y * qv[g].y + kd.z * qv[g].z +
                  kd.w * qv[g].w;
        d += __shfl_xor(d, 1);
        d += __shfl_xor(d, 2);
        d += __shfl_xor(d, 4);
        d += __shfl_xor(d, 8);
        d += __shfl_xor(d, 16);
        sc_[i][g] = valid ? d : -1e30f;
      }
    }
#pragma unroll
    for (int g = 0; g < GQ; ++g) {
      float tm = fmaxf(sc_[0][g], sc_[1][g]);
      float mnew = fmaxf(m[g], tm);
      float alpha = __expf(m[g] - mnew);
      float p0 = __expf(sc_[0][g] - mnew);
      float p1 = __expf(sc_[1][g] - mnew);
      l[g] = l[g] * alpha + (p0 + p1);
      oacc[g].x = oacc[g].x * alpha + p0 * vd_[0].x + p1 * vd_[1].x;
      oacc[g].y = oacc[g].y * alpha + p0 * vd_[0].y + p1 * vd_[1].y;
      oacc[g].z = oacc[g].z * alpha + p0 * vd_[0].z + p1 * vd_[1].z;
      oacc[g].w = oacc[g].w * alpha + p0 * vd_[0].w + p1 * vd_[1].w;
      m[g] = mnew;
    }
  }

  // ---- intra-WG combine of the 8 units (reuse ldsK as epilogue buffer)
  __syncthreads();  // all waves done with their buffers (drains vmcnt too)
  float (*so)[GQ][HD] = (float (*)[GQ][HD])ldsK;  // 8*4*128 = 4096 floats
#pragma unroll
  for (int g = 0; g < GQ; ++g)
    *(float4*)&so[unit][g][dbase] = oacc[g];
  if (lane == 0) {
#pragma unroll
    for (int g = 0; g < GQ; ++g) sml[unit][g] = make_float2(m[g], l[g]);
  }
  __syncthreads();

  if (tid < 128) {
    int g = tid >> 5;
    int ln = tid & 31;
    float M = -1e30f;
#pragma unroll
    for (int u = 0; u < UPW; ++u) M = fmaxf(M, sml[u][g].x);
    float L = 0.f;
    float4 acc = make_float4(0.f, 0.f, 0.f, 0.f);
#pragma unroll
    for (int u = 0; u < UPW; ++u) {
      float w = __expf(sml[u][g].x - M);
      L += sml[u][g].y * w;
      float4 t = *(const float4*)&so[u][g][ln * 4];
      acc.x += w * t.x;
      acc.y += w * t.y;
      acc.z += w * t.z;
      acc.w += w * t.w;
    }
    size_t ob = ((((size_t)s * NKV + h) * WPG + wgsub) * GQ + g) * HD + ln * 4;
    *(float4*)(o_part + ob) = acc;
    if (ln == 0)
      ml_part[(((size_t)s * NKV + h) * WPG + wgsub) * GQ + g] = make_float2(M, L);
  }
}

// ---------------------------------------------------------------------------
// Combine the WPG workgroup partials per (s,h)
// ---------------------------------------------------------------------------
__global__ void combine_splits(const float* __restrict__ o_part,
                               const float2* __restrict__ ml_part,
                               float* __restrict__ out) {
  int b = blockIdx.x;      // s*NKV + h
  int h = b % NKV;
  int s = b / NKV;
  int d = threadIdx.x;     // 0..127
#pragma unroll
  for (int g = 0; g < GQ; ++g) {
    float2 ml[WPG];
    float M = -1e30f;
#pragma unroll
    for (int i = 0; i < WPG; ++i) {
      ml[i] = ml_part[(((size_t)s * NKV + h) * WPG + i) * GQ + g];
      M = fmaxf(M, ml[i].x);
    }
    float L = 0.f;
    float acc = 0.f;
#pragma unroll
    for (int i = 0; i < WPG; ++i) {
      float w = __expf(ml[i].x - M);
      L += ml[i].y * w;
      acc += w * o_part[((((size_t)s * NKV + h) * WPG + i) * GQ + g) * HD + d];
    }
    out[((size_t)s * NH + h * GQ + g) * HD + d] = acc / L;
  }
}

// ---------------------------------------------------------------------------
extern "C" void kernel_launch(void* const* d_in, const int* in_sizes, int n_in,
                              void* d_out, int out_size, void* d_ws, size_t ws_size,
                              hipStream_t stream) {
  const float* q        = (const float*)d_in[0];
  const float* k        = (const float*)d_in[1];
  const float* v        = (const float*)d_in[2];
  const float* k_cache  = (const float*)d_in[3];
  const float* v_cache  = (const float*)d_in[4];
  const float* k_scale  = (const float*)d_in[5];
  const float* v_scale  = (const float*)d_in[6];
  const int*   btables  = (const int*)d_in[8];
  const int*   ctx_lens = (const int*)d_in[9];
  float*       out      = (float*)d_out;

  float*  o_part  = (float*)d_ws;
  float2* ml_part = (float2*)((char*)d_ws +
                     (size_t)SEQ * NKV * WPG * GQ * HD * sizeof(float));

  attn_split<<<SEQ * NKV * WPG, 256, 0, stream>>>(
      q, k, v, k_cache, v_cache, k_scale, v_scale, btables, ctx_lens,
      o_part, ml_part);

  combine_splits<<<SEQ * NKV, 128, 0, stream>>>(o_part, ml_part, out);
}